// Round 7
// baseline (338.251 us; speedup 1.0000x reference)
//
#include <hip/hip_runtime.h>
#include <stdint.h>

// set attention: N=32, L=256, D=20, H=2, Dh=20, fp32 I/O.
// Out batch b: Q from x[b], K/V from y[(b&31)*32 + (b>>5)]  (verified R2-R5).
// R7 = R6 structure (512 threads, 32 rows/wave -> halved per-wave live set,
// 4 waves/SIMD target) + R5's PROVEN numerics bit-for-bit (perm RNE pack,
// masked exp, explicit fp32 row sums + shfl reduction + sL broadcast, plain
// divide). R6's unverified deltas (cvt_pk builtin, ones-row denom, frcp,
// mask drop) are all reverted to isolate the NaN source.

#define NSET 32
#define SEQL 256
#define DM   20
#define NH   2
#define DH   20

typedef __attribute__((ext_vector_type(8))) short short8;
typedef __attribute__((ext_vector_type(4))) short short4v;
typedef __attribute__((ext_vector_type(4))) float f32x4;

#define MFMA32(a, b, c) __builtin_amdgcn_mfma_f32_16x16x32_bf16((a), (b), (c), 0, 0, 0)

#if __has_builtin(__builtin_amdgcn_mfma_f32_16x16x16bf16_1k)
#define MFMA16(a, b, c) __builtin_amdgcn_mfma_f32_16x16x16bf16_1k((a), (b), (c), 0, 0, 0)
#elif __has_builtin(__builtin_amdgcn_mfma_f32_16x16x16_bf16)
#define MFMA16(a, b, c) __builtin_amdgcn_mfma_f32_16x16x16_bf16((a), (b), (c), 0, 0, 0)
#else
static __device__ __forceinline__ f32x4 MFMA16(short4v a, short4v b, f32x4 c) {
    asm volatile("s_nop 1\n\tv_mfma_f32_16x16x16_bf16 %0, %1, %2, %0\n\ts_nop 7"
                 : "+v"(c) : "v"(a), "v"(b));
    return c;
}
#endif

__device__ __forceinline__ uint32_t bfbits_rne(float f) {
    uint32_t u = __float_as_uint(f);
    return ((u + 0x7fffu + ((u >> 16) & 1u)) >> 16) & 0xffffu;
}
// RNE-rounded bf16 bits left in the HIGH half (for v_perm pack)
__device__ __forceinline__ uint32_t rne_hi(float f) {
    uint32_t u = __float_as_uint(f);
    return u + 0x7fffu + ((u >> 16) & 1u);
}
__device__ __forceinline__ float fexp2(float x) {
    float r;
    asm("v_exp_f32 %0, %1" : "=v"(r) : "v"(x));
    return r;
}

// predicated b128 A/B-frag load from row-major [256][24] bf16 region
__device__ __forceinline__ short8 ldsA(const short* base, int row, int qd) {
    short8 f = {0, 0, 0, 0, 0, 0, 0, 0};
    if (qd < 3) f = *(const short8*)(base + row * 24 + qd * 8);
    return f;
}

// global fp32 row (20 floats, 16B-aligned) -> bf16 frag for k-quad qd
__device__ __forceinline__ short8 gfrag(const float* rowp, int qd) {
    short8 f = {0, 0, 0, 0, 0, 0, 0, 0};
    if (qd < 2) {
        float4 a = *(const float4*)(rowp + qd * 8);
        float4 b = *(const float4*)(rowp + qd * 8 + 4);
        f[0] = (short)bfbits_rne(a.x); f[1] = (short)bfbits_rne(a.y);
        f[2] = (short)bfbits_rne(a.z); f[3] = (short)bfbits_rne(a.w);
        f[4] = (short)bfbits_rne(b.x); f[5] = (short)bfbits_rne(b.y);
        f[6] = (short)bfbits_rne(b.z); f[7] = (short)bfbits_rne(b.w);
    } else if (qd == 2) {
        float4 a = *(const float4*)(rowp + 16);
        f[0] = (short)bfbits_rne(a.x); f[1] = (short)bfbits_rne(a.y);
        f[2] = (short)bfbits_rne(a.z); f[3] = (short)bfbits_rne(a.w);
    }
    return f;
}

// B-frag gather from global fp32 weight: f[j] = W[(qd*8+j)*ldn + col] * scl
__device__ __forceinline__ short8 gather_w(const float* W, int ldn, int col,
                                           int qd, float scl) {
    short8 f = {0, 0, 0, 0, 0, 0, 0, 0};
    if (col >= 0) {
#pragma unroll
        for (int j = 0; j < 8; ++j) {
            int k = qd * 8 + j;
            if (k < 20) f[j] = (short)bfbits_rne(W[k * ldn + col] * scl);
        }
    }
    return f;
}

__global__ __launch_bounds__(512, 4) void set_attn_v7(
    const float* __restrict__ x, const float* __restrict__ y,
    const float* __restrict__ wq, const float* __restrict__ wk,
    const float* __restrict__ wv, const float* __restrict__ wh,
    float* __restrict__ out)
{
    __shared__ __align__(16) short sQ[SEQL * 24];   // Q_h then O_h (wave-local), 12 KB
    __shared__ __align__(16) short sK[SEQL * 24];   // K_h, 12 KB
    __shared__ __align__(16) short sVt[20 * 264];   // V_h^T [d][s], 10.3 KB
    __shared__ float sL[256];                       // softmax denoms, 1 KB
    // total 35.3 KB

    const int tid  = threadIdx.x;
    const int lane = tid & 63;
    const int w    = tid >> 6;     // wave 0..7, owns rows w*32..w*32+31
    const int c    = lane & 15;
    const int qd   = lane >> 4;
    const int b    = blockIdx.x;
    const int bi   = b >> 5, bj = b & 31;

    // zero pad cols 20..23 once (persist across heads; rewrites touch cols<20)
    if (tid < 256) {
        *(uint2*)(sQ + tid * 24 + 20) = make_uint2(0u, 0u);
        *(uint2*)(sK + tid * 24 + 20) = make_uint2(0u, 0u);
    }

    const float QS = 0.22360679774997896f * 1.4426950408889634f;  // scale*log2(e)
    const int n0 = c;
    const int n1 = (16 + c < 20) ? 16 + c : -1;

    f32x4 outacc[2][2];
#pragma unroll
    for (int mt = 0; mt < 2; ++mt)
#pragma unroll
        for (int dt = 0; dt < 2; ++dt) outacc[mt][dt] = (f32x4){0.f, 0.f, 0.f, 0.f};

    for (int h = 0; h < NH; ++h) {
        if (h) __syncthreads();   // all waves done reading prev head's sK/sVt

        // ---- x,y frags (reloaded per head -> dead during s-loop) ----
        short8 xf[2], yf[2];
#pragma unroll
        for (int mt = 0; mt < 2; ++mt) {
            int row = w * 32 + mt * 16 + c;
            xf[mt] = gfrag(x + ((size_t)b * SEQL + row) * DM, qd);
            yf[mt] = gfrag(y + ((size_t)(bj * NSET + bi) * SEQL + row) * DM, qd);
        }
        // ---- weight B-frags for head h (softmax scale folded into WQ) ----
        short8 wqf[2], wkf[2], wvf[2];
        wqf[0] = gather_w(wq, 40, h * 20 + n0, qd, QS);
        wqf[1] = gather_w(wq, 40, (n1 >= 0) ? h * 20 + n1 : -1, qd, QS);
        wkf[0] = gather_w(wk, 40, h * 20 + n0, qd, 1.f);
        wkf[1] = gather_w(wk, 40, (n1 >= 0) ? h * 20 + n1 : -1, qd, 1.f);
        wvf[0] = gather_w(wv, 40, h * 20 + n0, qd, 1.f);
        wvf[1] = gather_w(wv, 40, (n1 >= 0) ? h * 20 + n1 : -1, qd, 1.f);

        // ---- projection for head h ----
#pragma unroll
        for (int mt = 0; mt < 2; ++mt) {
            int rbase = w * 32 + mt * 16;
#pragma unroll
            for (int dt = 0; dt < 2; ++dt) {
                f32x4 z = {0.f, 0.f, 0.f, 0.f};
                f32x4 qres = MFMA32(xf[mt], (dt == 0 ? wqf[0] : wqf[1]), z);
                f32x4 kres = MFMA32(yf[mt], (dt == 0 ? wkf[0] : wkf[1]), z);
                f32x4 vres = MFMA32(yf[mt], (dt == 0 ? wvf[0] : wvf[1]), z);
                int n = dt * 16 + c;
                if (n < 20) {
#pragma unroll
                    for (int reg = 0; reg < 4; ++reg) {
                        int row = rbase + qd * 4 + reg;
                        sQ[row * 24 + n] = (short)bfbits_rne(qres[reg]);
                        sK[row * 24 + n] = (short)bfbits_rne(kres[reg]);
                        sVt[n * 264 + row] = (short)bfbits_rne(vres[reg]);
                    }
                }
            }
        }
        __syncthreads();   // K_h, V_h^T visible to all waves

        // ---- attention ----
        short8 qb[2];
#pragma unroll
        for (int mt = 0; mt < 2; ++mt) qb[mt] = ldsA(sQ, w * 32 + mt * 16 + c, qd);

        f32x4 oacc[2][2];
#pragma unroll
        for (int mt = 0; mt < 2; ++mt)
#pragma unroll
            for (int dt = 0; dt < 2; ++dt) oacc[mt][dt] = (f32x4){0.f, 0.f, 0.f, 0.f};
        float ls[2] = {0.f, 0.f};

        for (int s0 = 0; s0 < SEQL; s0 += 32) {
            short8 kf0 = ldsA(sK, s0 + c, qd);
            short8 kf1 = ldsA(sK, s0 + 16 + c, qd);
            short4v vb[2][2];
#pragma unroll
            for (int dt = 0; dt < 2; ++dt) {
                int d = dt * 16 + c;
#pragma unroll
                for (int st = 0; st < 2; ++st) {
                    uint2 u = make_uint2(0u, 0u);
                    if (d < 20)
                        u = *(const uint2*)(sVt + d * 264 + s0 + st * 16 + qd * 4);
                    short4v t; *(uint2*)&t = u;
                    vb[st][dt] = t;
                }
            }
#pragma unroll
            for (int mt = 0; mt < 2; ++mt) {
#pragma unroll
                for (int st = 0; st < 2; ++st) {
                    f32x4 z = {0.f, 0.f, 0.f, 0.f};
                    f32x4 sacc = MFMA32((st == 0 ? kf0 : kf1), qb[mt], z);
                    float p0 = (sacc[0] != 0.f) ? fexp2(sacc[0]) : 0.f;  // zero-logit mask
                    float p1 = (sacc[1] != 0.f) ? fexp2(sacc[1]) : 0.f;
                    float p2 = (sacc[2] != 0.f) ? fexp2(sacc[2]) : 0.f;
                    float p3 = (sacc[3] != 0.f) ? fexp2(sacc[3]) : 0.f;
                    ls[mt] += (p0 + p1) + (p2 + p3);
                    short4v pf;
                    *(uint2*)&pf = make_uint2(
                        __builtin_amdgcn_perm(rne_hi(p1), rne_hi(p0), 0x07060302u),
                        __builtin_amdgcn_perm(rne_hi(p3), rne_hi(p2), 0x07060302u));
                    oacc[mt][0] = MFMA16(pf, vb[st][0], oacc[mt][0]);
                    oacc[mt][1] = MFMA16(pf, vb[st][1], oacc[mt][1]);
                }
            }
        }

        // ---- softmax denominators: reduce over qd groups, broadcast via sL ----
#pragma unroll
        for (int mt = 0; mt < 2; ++mt) {
            ls[mt] += __shfl_xor(ls[mt], 16, 64);
            ls[mt] += __shfl_xor(ls[mt], 32, 64);
        }
        // lane (qd,c) holds full sum for row w*32 + qd*16 + c (qd<2 valid)
        float sel = (qd == 0) ? ls[0] : ls[1];
        if (qd < 2) sL[w * 32 + qd * 16 + c] = sel;   // same-wave producer/consumer

        // ---- normalize O, overwrite Q_h (wave-local rows) ----
#pragma unroll
        for (int mt = 0; mt < 2; ++mt) {
            float inv[4];
#pragma unroll
            for (int reg = 0; reg < 4; ++reg)
                inv[reg] = 1.f / (sL[w * 32 + mt * 16 + qd * 4 + reg] + 1e-10f);
#pragma unroll
            for (int dt = 0; dt < 2; ++dt) {
                int n = dt * 16 + c;
                if (n < 20) {
#pragma unroll
                    for (int reg = 0; reg < 4; ++reg) {
                        int row = w * 32 + mt * 16 + qd * 4 + reg;
                        sQ[row * 24 + n] = (short)bfbits_rne(oacc[mt][dt][reg] * inv[reg]);
                    }
                }
            }
        }

        // ---- out-projection: outacc += O_h * WH[h*20:(h+1)*20, :] ----
        short8 whf0 = gather_w(wh + h * 400, 20, n0, qd, 1.f);
        short8 whf1 = gather_w(wh + h * 400, 20, n1, qd, 1.f);
#pragma unroll
        for (int mt = 0; mt < 2; ++mt) {
            short8 of = ldsA(sQ, w * 32 + mt * 16 + c, qd);   // same-wave rows
            outacc[mt][0] = MFMA32(of, whf0, outacc[mt][0]);
            outacc[mt][1] = MFMA32(of, whf1, outacc[mt][1]);
        }
    }

    // ---- store fp32 output ----
    float* ob = out + (size_t)b * (SEQL * DH);
#pragma unroll
    for (int mt = 0; mt < 2; ++mt)
#pragma unroll
        for (int dt = 0; dt < 2; ++dt) {
            int n = dt * 16 + c;
            if (n < 20) {
#pragma unroll
                for (int reg = 0; reg < 4; ++reg) {
                    int row = w * 32 + mt * 16 + qd * 4 + reg;
                    ob[row * 20 + n] = outacc[mt][dt][reg];
                }
            }
        }
}

extern "C" void kernel_launch(void* const* d_in, const int* in_sizes, int n_in,
                              void* d_out, int out_size, void* d_ws, size_t ws_size,
                              hipStream_t stream) {
    const float* x  = (const float*)d_in[0];
    const float* y  = (const float*)d_in[1];
    const float* wq = (const float*)d_in[2];
    const float* wk = (const float*)d_in[3];
    const float* wv = (const float*)d_in[4];
    const float* wh = (const float*)d_in[5];
    float* out = (float*)d_out;

    set_attn_v7<<<dim3(NSET * NSET), dim3(512), 0, stream>>>(x, y, wq, wk, wv, wh, out);
}

// Round 8
// 186.733 us; speedup vs baseline: 1.8114x; 1.8114x over previous
//
#include <hip/hip_runtime.h>
#include <stdint.h>

// set attention: N=32, L=256, D=20, H=2, Dh=20, fp32 I/O.
// Out batch b: Q from x[b], K/V from y[(b&31)*32 + (b>>5)]  (verified R2-R7).
// R8 = R5 byte-identical except __launch_bounds__(256,2): measured evidence
// (R4 vs R5 vs R7) shows any 128-reg cap collapses the allocator to 64 VGPR
// + ~1KB/thread scratch (R5 +190MB, R7 +580MB HBM traffic). Natural alloc is
// ~88-120 regs -> with 35.3 KB LDS the HW reaches 3-4 blocks/CU on its own.
//   S^T = K*Qs^T (16x16x32, softmax scale folded into WQ gather)
//   P in registers (S^T C-layout == 16x16x16 A-layout) -> PV 16x16x16
//   O_h overwrites Q_h in LDS (wave-local rows) -> out-proj 16x16x32.

#define NSET 32
#define SEQL 256
#define DM   20
#define NH   2
#define DH   20

typedef __attribute__((ext_vector_type(8))) short short8;
typedef __attribute__((ext_vector_type(4))) short short4v;
typedef __attribute__((ext_vector_type(4))) float f32x4;

#define MFMA32(a, b, c) __builtin_amdgcn_mfma_f32_16x16x32_bf16((a), (b), (c), 0, 0, 0)

#if __has_builtin(__builtin_amdgcn_mfma_f32_16x16x16bf16_1k)
#define MFMA16(a, b, c) __builtin_amdgcn_mfma_f32_16x16x16bf16_1k((a), (b), (c), 0, 0, 0)
#elif __has_builtin(__builtin_amdgcn_mfma_f32_16x16x16_bf16)
#define MFMA16(a, b, c) __builtin_amdgcn_mfma_f32_16x16x16_bf16((a), (b), (c), 0, 0, 0)
#else
static __device__ __forceinline__ f32x4 MFMA16(short4v a, short4v b, f32x4 c) {
    asm volatile("s_nop 1\n\tv_mfma_f32_16x16x16_bf16 %0, %1, %2, %0\n\ts_nop 7"
                 : "+v"(c) : "v"(a), "v"(b));
    return c;
}
#endif

__device__ __forceinline__ uint32_t bfbits_rne(float f) {
    uint32_t u = __float_as_uint(f);
    return ((u + 0x7fffu + ((u >> 16) & 1u)) >> 16) & 0xffffu;
}
// RNE-rounded bf16 bits left in the HIGH half (for v_perm pack)
__device__ __forceinline__ uint32_t rne_hi(float f) {
    uint32_t u = __float_as_uint(f);
    return u + 0x7fffu + ((u >> 16) & 1u);
}
__device__ __forceinline__ float fexp2(float x) {
    float r;
    asm("v_exp_f32 %0, %1" : "=v"(r) : "v"(x));
    return r;
}

// predicated b128 A/B-frag load from row-major [256][24] bf16 region
__device__ __forceinline__ short8 ldsA(const short* base, int row, int qd) {
    short8 f = {0, 0, 0, 0, 0, 0, 0, 0};
    if (qd < 3) f = *(const short8*)(base + row * 24 + qd * 8);
    return f;
}

// global fp32 row (20 floats, 16B-aligned) -> bf16 frag for k-quad qd
__device__ __forceinline__ short8 gfrag(const float* rowp, int qd) {
    short8 f = {0, 0, 0, 0, 0, 0, 0, 0};
    if (qd < 2) {
        float4 a = *(const float4*)(rowp + qd * 8);
        float4 b = *(const float4*)(rowp + qd * 8 + 4);
        f[0] = (short)bfbits_rne(a.x); f[1] = (short)bfbits_rne(a.y);
        f[2] = (short)bfbits_rne(a.z); f[3] = (short)bfbits_rne(a.w);
        f[4] = (short)bfbits_rne(b.x); f[5] = (short)bfbits_rne(b.y);
        f[6] = (short)bfbits_rne(b.z); f[7] = (short)bfbits_rne(b.w);
    } else if (qd == 2) {
        float4 a = *(const float4*)(rowp + 16);
        f[0] = (short)bfbits_rne(a.x); f[1] = (short)bfbits_rne(a.y);
        f[2] = (short)bfbits_rne(a.z); f[3] = (short)bfbits_rne(a.w);
    }
    return f;
}

// B-frag gather from global fp32 weight: f[j] = W[(qd*8+j)*ldn + col] * scl
__device__ __forceinline__ short8 gather_w(const float* W, int ldn, int col,
                                           int qd, float scl) {
    short8 f = {0, 0, 0, 0, 0, 0, 0, 0};
    if (col >= 0) {
#pragma unroll
        for (int j = 0; j < 8; ++j) {
            int k = qd * 8 + j;
            if (k < 20) f[j] = (short)bfbits_rne(W[k * ldn + col] * scl);
        }
    }
    return f;
}

__global__ __launch_bounds__(256, 2) void set_attn_v8(
    const float* __restrict__ x, const float* __restrict__ y,
    const float* __restrict__ wq, const float* __restrict__ wk,
    const float* __restrict__ wv, const float* __restrict__ wh,
    float* __restrict__ out)
{
    __shared__ __align__(16) short sQ[SEQL * 24];   // Q_h then O_h (wave-local), 12 KB
    __shared__ __align__(16) short sK[SEQL * 24];   // K_h, 12 KB
    __shared__ __align__(16) short sVt[20 * 264];   // V_h^T [d][s], 10.3 KB
    __shared__ float sL[256];                       // softmax denoms, 1 KB
    // total 35.3 KB -> 4 blocks/CU by LDS

    const int tid  = threadIdx.x;
    const int lane = tid & 63;
    const int w    = tid >> 6;     // wave 0..3, owns rows w*64..w*64+63
    const int c    = lane & 15;
    const int qd   = lane >> 4;
    const int b    = blockIdx.x;
    const int bi   = b >> 5, bj = b & 31;

    // zero pad cols 20..23 once (persist across heads; rewrites touch cols<20 only)
    *(uint2*)(sQ + tid * 24 + 20) = make_uint2(0u, 0u);
    *(uint2*)(sK + tid * 24 + 20) = make_uint2(0u, 0u);

    const float QS = 0.22360679774997896f * 1.4426950408889634f;  // scale*log2(e)
    const int n0 = c;
    const int n1 = (16 + c < 20) ? 16 + c : -1;

    f32x4 outacc[4][2];
#pragma unroll
    for (int mt = 0; mt < 4; ++mt)
#pragma unroll
        for (int dt = 0; dt < 2; ++dt) outacc[mt][dt] = (f32x4){0.f, 0.f, 0.f, 0.f};

    for (int h = 0; h < NH; ++h) {
        if (h) __syncthreads();   // all waves done reading prev head's sK/sVt

        // ---- x,y frags (reloaded per head -> dead during s-loop) ----
        short8 xf[4], yf[4];
#pragma unroll
        for (int mt = 0; mt < 4; ++mt) {
            int row = w * 64 + mt * 16 + c;
            xf[mt] = gfrag(x + ((size_t)b * SEQL + row) * DM, qd);
            yf[mt] = gfrag(y + ((size_t)(bj * NSET + bi) * SEQL + row) * DM, qd);
        }
        // ---- weight B-frags for head h (softmax scale folded into WQ) ----
        short8 wqf[2], wkf[2], wvf[2];
        wqf[0] = gather_w(wq, 40, h * 20 + n0, qd, QS);
        wqf[1] = gather_w(wq, 40, (n1 >= 0) ? h * 20 + n1 : -1, qd, QS);
        wkf[0] = gather_w(wk, 40, h * 20 + n0, qd, 1.f);
        wkf[1] = gather_w(wk, 40, (n1 >= 0) ? h * 20 + n1 : -1, qd, 1.f);
        wvf[0] = gather_w(wv, 40, h * 20 + n0, qd, 1.f);
        wvf[1] = gather_w(wv, 40, (n1 >= 0) ? h * 20 + n1 : -1, qd, 1.f);

        // ---- projection for head h ----
#pragma unroll
        for (int mt = 0; mt < 4; ++mt) {
            int rbase = w * 64 + mt * 16;
#pragma unroll
            for (int dt = 0; dt < 2; ++dt) {
                f32x4 z = {0.f, 0.f, 0.f, 0.f};
                f32x4 qres = MFMA32(xf[mt], (dt == 0 ? wqf[0] : wqf[1]), z);
                f32x4 kres = MFMA32(yf[mt], (dt == 0 ? wkf[0] : wkf[1]), z);
                f32x4 vres = MFMA32(yf[mt], (dt == 0 ? wvf[0] : wvf[1]), z);
                int n = dt * 16 + c;
                if (n < 20) {
#pragma unroll
                    for (int reg = 0; reg < 4; ++reg) {
                        int row = rbase + qd * 4 + reg;
                        sQ[row * 24 + n] = (short)bfbits_rne(qres[reg]);
                        sK[row * 24 + n] = (short)bfbits_rne(kres[reg]);
                        sVt[n * 264 + row] = (short)bfbits_rne(vres[reg]);
                    }
                }
            }
        }
        __syncthreads();   // K_h, V_h^T visible to all waves

        // ---- attention ----
        short8 qb[4];
#pragma unroll
        for (int mt = 0; mt < 4; ++mt) qb[mt] = ldsA(sQ, w * 64 + mt * 16 + c, qd);

        f32x4 oacc[4][2];
#pragma unroll
        for (int mt = 0; mt < 4; ++mt)
#pragma unroll
            for (int dt = 0; dt < 2; ++dt) oacc[mt][dt] = (f32x4){0.f, 0.f, 0.f, 0.f};
        float ls[4] = {0.f, 0.f, 0.f, 0.f};

        for (int s0 = 0; s0 < SEQL; s0 += 32) {
            short8 kf0 = ldsA(sK, s0 + c, qd);
            short8 kf1 = ldsA(sK, s0 + 16 + c, qd);
            short4v vb[2][2];
#pragma unroll
            for (int dt = 0; dt < 2; ++dt) {
                int d = dt * 16 + c;
#pragma unroll
                for (int st = 0; st < 2; ++st) {
                    uint2 u = make_uint2(0u, 0u);
                    if (d < 20)
                        u = *(const uint2*)(sVt + d * 264 + s0 + st * 16 + qd * 4);
                    short4v t; *(uint2*)&t = u;
                    vb[st][dt] = t;
                }
            }
#pragma unroll
            for (int mt = 0; mt < 4; ++mt) {
#pragma unroll
                for (int st = 0; st < 2; ++st) {
                    f32x4 z = {0.f, 0.f, 0.f, 0.f};
                    f32x4 sacc = MFMA32((st == 0 ? kf0 : kf1), qb[mt], z);
                    float p0 = (sacc[0] != 0.f) ? fexp2(sacc[0]) : 0.f;  // zero-logit mask
                    float p1 = (sacc[1] != 0.f) ? fexp2(sacc[1]) : 0.f;
                    float p2 = (sacc[2] != 0.f) ? fexp2(sacc[2]) : 0.f;
                    float p3 = (sacc[3] != 0.f) ? fexp2(sacc[3]) : 0.f;
                    ls[mt] += (p0 + p1) + (p2 + p3);
                    short4v pf;
                    *(uint2*)&pf = make_uint2(
                        __builtin_amdgcn_perm(rne_hi(p1), rne_hi(p0), 0x07060302u),
                        __builtin_amdgcn_perm(rne_hi(p3), rne_hi(p2), 0x07060302u));
                    oacc[mt][0] = MFMA16(pf, vb[st][0], oacc[mt][0]);
                    oacc[mt][1] = MFMA16(pf, vb[st][1], oacc[mt][1]);
                }
            }
        }

        // ---- softmax denominators: reduce over qd groups, broadcast via sL ----
#pragma unroll
        for (int mt = 0; mt < 4; ++mt) {
            ls[mt] += __shfl_xor(ls[mt], 16, 64);
            ls[mt] += __shfl_xor(ls[mt], 32, 64);
        }
        float sel = (qd == 0) ? ls[0] : (qd == 1) ? ls[1] : (qd == 2) ? ls[2] : ls[3];
        sL[w * 64 + lane] = sel;   // sL[w*64+i] = denom of row w*64+i (same-wave)

        // ---- normalize O, overwrite Q_h (wave-local rows) ----
#pragma unroll
        for (int mt = 0; mt < 4; ++mt) {
            float inv[4];
#pragma unroll
            for (int reg = 0; reg < 4; ++reg)
                inv[reg] = 1.f / (sL[w * 64 + mt * 16 + qd * 4 + reg] + 1e-10f);
#pragma unroll
            for (int dt = 0; dt < 2; ++dt) {
                int n = dt * 16 + c;
                if (n < 20) {
#pragma unroll
                    for (int reg = 0; reg < 4; ++reg) {
                        int row = w * 64 + mt * 16 + qd * 4 + reg;
                        sQ[row * 24 + n] = (short)bfbits_rne(oacc[mt][dt][reg] * inv[reg]);
                    }
                }
            }
        }

        // ---- out-projection: outacc += O_h * WH[h*20:(h+1)*20, :] ----
        short8 whf0 = gather_w(wh + h * 400, 20, n0, qd, 1.f);
        short8 whf1 = gather_w(wh + h * 400, 20, n1, qd, 1.f);
#pragma unroll
        for (int mt = 0; mt < 4; ++mt) {
            short8 of = ldsA(sQ, w * 64 + mt * 16 + c, qd);   // same-wave rows
            outacc[mt][0] = MFMA32(of, whf0, outacc[mt][0]);
            outacc[mt][1] = MFMA32(of, whf1, outacc[mt][1]);
        }
    }

    // ---- store fp32 output ----
    float* ob = out + (size_t)b * (SEQL * DH);
#pragma unroll
    for (int mt = 0; mt < 4; ++mt)
#pragma unroll
        for (int dt = 0; dt < 2; ++dt) {
            int n = dt * 16 + c;
            if (n < 20) {
#pragma unroll
                for (int reg = 0; reg < 4; ++reg) {
                    int row = w * 64 + mt * 16 + qd * 4 + reg;
                    ob[row * 20 + n] = outacc[mt][dt][reg];
                }
            }
        }
}

extern "C" void kernel_launch(void* const* d_in, const int* in_sizes, int n_in,
                              void* d_out, int out_size, void* d_ws, size_t ws_size,
                              hipStream_t stream) {
    const float* x  = (const float*)d_in[0];
    const float* y  = (const float*)d_in[1];
    const float* wq = (const float*)d_in[2];
    const float* wk = (const float*)d_in[3];
    const float* wv = (const float*)d_in[4];
    const float* wh = (const float*)d_in[5];
    float* out = (float*)d_out;

    set_attn_v8<<<dim3(NSET * NSET), dim3(SEQL), 0, stream>>>(x, y, wq, wk, wv, wh, out);
}